// Round 2
// baseline (542.697 us; speedup 1.0000x reference)
//
#include <hip/hip_runtime.h>

#define HW 16384
#define CIN 512
#define PL 256
#define EPSF 1e-5f

using half8  = __attribute__((ext_vector_type(8))) _Float16;
using half4v = __attribute__((ext_vector_type(4))) _Float16;
using f32x4  = __attribute__((ext_vector_type(4))) float;

// ---------- kernel 0a: weights f32 -> f16 hi + scaled-lo, layout [3*256][512] (t,p,g)
__global__ __launch_bounds__(256) void k_wcvt(const float* __restrict__ Wt,
                                              const float* __restrict__ Wp,
                                              const float* __restrict__ Wg,
                                              _Float16* __restrict__ Wh,
                                              _Float16* __restrict__ Wlo) {
  int idx = blockIdx.x * 256 + threadIdx.x;           // < 768*512
  int row = idx >> 9, k = idx & 511;
  const float* src = (row < 256) ? Wt : ((row < 512) ? Wp : Wg);
  float v = src[((row & 255) << 9) + k];
  _Float16 hi = (_Float16)v;
  Wh[idx] = hi;
  Wlo[idx] = (_Float16)((v - (float)hi) * 1024.f);
}

// ---------- kernel 0b: x [b][c][hw] f32 -> xT [b][hw][c] f16 hi + scaled-lo
__global__ __launch_bounds__(256) void k_xpose(const float* __restrict__ x,
                                               _Float16* __restrict__ xT,
                                               _Float16* __restrict__ xlo) {
  __shared__ float lds[64 * 65];
  int b = blockIdx.z;
  int cb = blockIdx.y << 6;
  int nb = blockIdx.x << 6;
  int tid = threadIdx.x;
  int q = tid & 15;
  int p = tid >> 4;
  const float* xb = x + ((size_t)b * CIN + cb) * HW + nb;
#pragma unroll
  for (int i = 0; i < 4; ++i) {
    int c = p + i * 16;
    float4 v = *reinterpret_cast<const float4*>(xb + (size_t)c * HW + (q << 2));
    lds[c * 65 + (q << 2) + 0] = v.x;
    lds[c * 65 + (q << 2) + 1] = v.y;
    lds[c * 65 + (q << 2) + 2] = v.z;
    lds[c * 65 + (q << 2) + 3] = v.w;
  }
  __syncthreads();
  size_t obase = ((size_t)b * HW + nb) * CIN + cb;
#pragma unroll
  for (int i = 0; i < 4; ++i) {
    int n = p + i * 16;
    half4v h, l;
#pragma unroll
    for (int j = 0; j < 4; ++j) {
      float v = lds[(q * 4 + j) * 65 + n];
      _Float16 hi = (_Float16)v;
      h[j] = hi;
      l[j] = (_Float16)((v - (float)hi) * 1024.f);
    }
    *reinterpret_cast<half4v*>(xT + obase + (size_t)n * CIN + (q << 2)) = h;
    *reinterpret_cast<half4v*>(xlo + obase + (size_t)n * CIN + (q << 2)) = l;
  }
}

// ---------- kernel 1a: t GEMM (hi only) + GN stats + fp16 t store
__global__ __launch_bounds__(512) void k_t(const _Float16* __restrict__ xT,
                                           const _Float16* __restrict__ Wh,
                                           _Float16* __restrict__ t_ws,
                                           float* __restrict__ tsum,
                                           float* __restrict__ tsq) {
  int tid = threadIdx.x;
  int wave = tid >> 6, lane = tid & 63;
  int l15 = lane & 15, l4 = lane >> 4;
  int b = blockIdx.y;
  int nb = blockIdx.x << 6;
  const _Float16* xTb = xT + (size_t)b * HW * CIN;

  const half8* ap[4];
#pragma unroll
  for (int nf = 0; nf < 4; ++nf)
    ap[nf] = reinterpret_cast<const half8*>(xTb + (size_t)(nb + nf * 16 + l15) * CIN + l4 * 8);
  const half8* bp[2];
#pragma unroll
  for (int ob = 0; ob < 2; ++ob) {
    int row = wave * 32 + ob * 16 + l15;   // t rows 0..255
    bp[ob] = reinterpret_cast<const half8*>(Wh + (size_t)row * CIN + l4 * 8);
  }

  f32x4 acc[2][4];
#pragma unroll
  for (int ob = 0; ob < 2; ++ob)
#pragma unroll
    for (int nf = 0; nf < 4; ++nf) acc[ob][nf] = f32x4{0.f, 0.f, 0.f, 0.f};

#pragma unroll
  for (int ks = 0; ks < 16; ++ks) {
    half8 af[4], bf[2];
#pragma unroll
    for (int nf = 0; nf < 4; ++nf) af[nf] = ap[nf][ks * 4];
#pragma unroll
    for (int ob = 0; ob < 2; ++ob) bf[ob] = bp[ob][ks * 4];
#pragma unroll
    for (int ob = 0; ob < 2; ++ob)
#pragma unroll
      for (int nf = 0; nf < 4; ++nf)
        acc[ob][nf] = __builtin_amdgcn_mfma_f32_16x16x32_f16(af[nf], bf[ob], acc[ob][nf], 0, 0, 0);
  }

  float* tsb = tsum + b * PL;
  float* tqb = tsq + b * PL;
#pragma unroll
  for (int ob = 0; ob < 2; ++ob) {
    float st = 0.f, sq = 0.f;
#pragma unroll
    for (int nf = 0; nf < 4; ++nf)
#pragma unroll
      for (int r = 0; r < 4; ++r) {
        float tv = acc[ob][nf][r];
        st += tv;
        sq += tv * tv;
      }
    st += __shfl_xor(st, 16, 64); st += __shfl_xor(st, 32, 64);
    sq += __shfl_xor(sq, 16, 64); sq += __shfl_xor(sq, 32, 64);
    if (l4 == 0) {
      int o = wave * 32 + ob * 16 + l15;
      atomicAdd(tsb + o, st);
      atomicAdd(tqb + o, sq);
    }
  }

  __shared__ _Float16 tl[256 * 72];
#pragma unroll
  for (int ob = 0; ob < 2; ++ob)
#pragma unroll
    for (int nf = 0; nf < 4; ++nf)
#pragma unroll
      for (int r = 0; r < 4; ++r) {
        int o_l = wave * 32 + ob * 16 + l15;
        int n_l = nf * 16 + l4 * 4 + r;
        tl[o_l * 72 + n_l] = (_Float16)acc[ob][nf][r];
      }
  __syncthreads();
  _Float16* tb = t_ws + (((size_t)b * PL) << 14) + nb;
  for (int idx = tid; idx < 256 * 16; idx += 512) {
    int row = idx >> 4, seg = idx & 15;
    *reinterpret_cast<uint2*>(tb + (size_t)row * HW + (seg << 2)) =
        *reinterpret_cast<const uint2*>(&tl[row * 72 + (seg << 2)]);
  }
}

// ---------- kernel 1b: att via split-precision p,g GEMM. No stores, only atomics.
// p = p_hi + 2^-10 * p_lo, where p_lo accumulates x_lo_s*W_hi + x_hi*W_lo_s.
__global__ __launch_bounds__(512) void k_att(const _Float16* __restrict__ xT,
                                             const _Float16* __restrict__ xlo,
                                             const _Float16* __restrict__ Wh,
                                             const _Float16* __restrict__ Wlo,
                                             float* __restrict__ att) {
  int tid = threadIdx.x;
  int wave = tid >> 6, lane = tid & 63;
  int l15 = lane & 15, l4 = lane >> 4;
  int b = blockIdx.y;
  int nb = blockIdx.x << 5;                      // n-tile = 32
  size_t xoff = (size_t)b * HW * CIN;

  const half8 *ah[2], *al[2];
#pragma unroll
  for (int nf = 0; nf < 2; ++nf) {
    size_t off = xoff + (size_t)(nb + nf * 16 + l15) * CIN + l4 * 8;
    ah[nf] = reinterpret_cast<const half8*>(xT + off);
    al[nf] = reinterpret_cast<const half8*>(xlo + off);
  }
  const half8 *bph[2], *bpl[2], *bgh[2], *bgl[2];
#pragma unroll
  for (int ob = 0; ob < 2; ++ob) {
    size_t rp = (size_t)(PL + wave * 32 + ob * 16 + l15) * CIN + l4 * 8;
    size_t rg = (size_t)(2 * PL + wave * 32 + ob * 16 + l15) * CIN + l4 * 8;
    bph[ob] = reinterpret_cast<const half8*>(Wh + rp);
    bpl[ob] = reinterpret_cast<const half8*>(Wlo + rp);
    bgh[ob] = reinterpret_cast<const half8*>(Wh + rg);
    bgl[ob] = reinterpret_cast<const half8*>(Wlo + rg);
  }

  f32x4 ph[2][2], pl[2][2], gh[2][2], gl[2][2];
#pragma unroll
  for (int ob = 0; ob < 2; ++ob)
#pragma unroll
    for (int nf = 0; nf < 2; ++nf) {
      ph[ob][nf] = f32x4{0.f, 0.f, 0.f, 0.f};
      pl[ob][nf] = f32x4{0.f, 0.f, 0.f, 0.f};
      gh[ob][nf] = f32x4{0.f, 0.f, 0.f, 0.f};
      gl[ob][nf] = f32x4{0.f, 0.f, 0.f, 0.f};
    }

#pragma unroll
  for (int ks = 0; ks < 16; ++ks) {
    half8 fah[2], fal[2];
#pragma unroll
    for (int nf = 0; nf < 2; ++nf) { fah[nf] = ah[nf][ks * 4]; fal[nf] = al[nf][ks * 4]; }
#pragma unroll
    for (int ob = 0; ob < 2; ++ob) {
      half8 fbph = bph[ob][ks * 4];
      half8 fbpl = bpl[ob][ks * 4];
      half8 fbgh = bgh[ob][ks * 4];
      half8 fbgl = bgl[ob][ks * 4];
#pragma unroll
      for (int nf = 0; nf < 2; ++nf) {
        ph[ob][nf] = __builtin_amdgcn_mfma_f32_16x16x32_f16(fah[nf], fbph, ph[ob][nf], 0, 0, 0);
        pl[ob][nf] = __builtin_amdgcn_mfma_f32_16x16x32_f16(fal[nf], fbph, pl[ob][nf], 0, 0, 0);
        pl[ob][nf] = __builtin_amdgcn_mfma_f32_16x16x32_f16(fah[nf], fbpl, pl[ob][nf], 0, 0, 0);
        gh[ob][nf] = __builtin_amdgcn_mfma_f32_16x16x32_f16(fah[nf], fbgh, gh[ob][nf], 0, 0, 0);
        gl[ob][nf] = __builtin_amdgcn_mfma_f32_16x16x32_f16(fal[nf], fbgh, gl[ob][nf], 0, 0, 0);
        gl[ob][nf] = __builtin_amdgcn_mfma_f32_16x16x32_f16(fah[nf], fbgl, gl[ob][nf], 0, 0, 0);
      }
    }
  }

  const float S = 0.0009765625f;  // 2^-10
  float* attb = att + b * PL;
#pragma unroll
  for (int ob = 0; ob < 2; ++ob) {
    float sa = 0.f;
#pragma unroll
    for (int nf = 0; nf < 2; ++nf)
#pragma unroll
      for (int r = 0; r < 4; ++r) {
        float pv = ph[ob][nf][r] + S * pl[ob][nf][r];
        float gv = gh[ob][nf][r] + S * gl[ob][nf][r];
        sa += pv * gv;
      }
    sa += __shfl_xor(sa, 16, 64); sa += __shfl_xor(sa, 32, 64);
    if (l4 == 0) atomicAdd(attb + wave * 32 + ob * 16 + l15, sa);
  }
}

// ---------- kernel 2: graph math (one block, 1024 threads)
__global__ __launch_bounds__(1024) void k_graph(
    const float* __restrict__ att, const float* __restrict__ tsum, const float* __restrict__ tsq,
    const float* __restrict__ W_adj, const float* __restrict__ bnag, const float* __restrict__ bnab,
    const float* __restrict__ bnam, const float* __restrict__ bnav,
    const float* __restrict__ W_wg, const float* __restrict__ bwgg, const float* __restrict__ bwgb,
    const float* __restrict__ bwgm, const float* __restrict__ bwgv,
    const float* __restrict__ Wz, const float* __restrict__ gng, const float* __restrict__ gnb,
    float* __restrict__ sA, float* __restrict__ sB) {
  __shared__ float att_l[4 * 256];
  __shared__ float z_l[4 * 256];
  __shared__ float zv_l[4 * 256];
  int tid = threadIdx.x;
  att_l[tid] = att[tid];
  __syncthreads();
  int b = tid >> 8, r = tid & 255, i = r >> 3, k = r & 7;
  float z1 = 0.f;
#pragma unroll
  for (int m = 0; m < 32; ++m) z1 += W_adj[i * 32 + m] * att_l[b * 256 + k * 32 + m];
  float inv = rsqrtf(bnav[i] + EPSF);
  float z = (z1 - bnam[i]) * inv * bnag[i] + bnab[i];
  z = fmaxf(z, 0.f) + att_l[b * 256 + k * 32 + i];
  z_l[b * 256 + i * 8 + k] = z;
  __syncthreads();
  float z2 = 0.f;
#pragma unroll
  for (int e = 0; e < 8; ++e) z2 += W_wg[k * 8 + e] * z_l[b * 256 + i * 8 + e];
  float inv2 = rsqrtf(bwgv[k] + EPSF);
  z2 = (z2 - bwgm[k]) * inv2 * bwgg[k] + bwgb[k];
  zv_l[b * 256 + i * 8 + k] = fmaxf(z2, 0.f);
  __syncthreads();
  int g = r;
  float s = zv_l[b * 256 + g];
  float m1 = tsum[b * 256 + g] * (1.f / 16384.f);
  float m2 = tsq[b * 256 + g] * (1.f / 16384.f);
  float a0 = Wz[2 * g] * s, a1 = Wz[2 * g + 1] * s;
  float mu = 0.5f * (a0 + a1) * m1;
  float ey2 = 0.5f * (a0 * a0 + a1 * a1) * m2;
  float var = ey2 - mu * mu;
  float invg = rsqrtf(var + EPSF);
  int c = b * CIN + 2 * g;
  sA[c]     = a0 * invg * gng[2 * g];
  sA[c + 1] = a1 * invg * gng[2 * g + 1];
  sB[c]     = gnb[2 * g]     - mu * invg * gng[2 * g];
  sB[c + 1] = gnb[2 * g + 1] - mu * invg * gng[2 * g + 1];
}

// ---------- kernel 3: out[b,c,hw] = sA[b,c]*t[b,c/2,hw] + sB[b,c] + x[b,c,hw]
__global__ __launch_bounds__(256) void k_out(const _Float16* __restrict__ t_ws,
                                             const float* __restrict__ x,
                                             const float* __restrict__ sA,
                                             const float* __restrict__ sB,
                                             float* __restrict__ out) {
  int blk = blockIdx.x;                 // 16384 = 4b * 256g * 16
  int b = blk >> 12;
  int g = (blk >> 4) & 255;
  int hw0 = (((blk & 15) << 8) + threadIdx.x) << 2;
  half4v tv = *reinterpret_cast<const half4v*>(t_ws + (((size_t)(b * PL + g)) << 14) + hw0);
  size_t xoff = (((size_t)(b * CIN + 2 * g)) << 14) + hw0;
  float4 x0 = *reinterpret_cast<const float4*>(x + xoff);
  float4 x1 = *reinterpret_cast<const float4*>(x + xoff + HW);
  int c = b * CIN + 2 * g;
  float s0 = sA[c], s1 = sA[c + 1], b0 = sB[c], b1 = sB[c + 1];
  float t0 = (float)tv[0], t1 = (float)tv[1], t2 = (float)tv[2], t3 = (float)tv[3];
  float4 o0, o1;
  o0.x = fmaf(s0, t0, x0.x + b0); o0.y = fmaf(s0, t1, x0.y + b0);
  o0.z = fmaf(s0, t2, x0.z + b0); o0.w = fmaf(s0, t3, x0.w + b0);
  o1.x = fmaf(s1, t0, x1.x + b1); o1.y = fmaf(s1, t1, x1.y + b1);
  o1.z = fmaf(s1, t2, x1.z + b1); o1.w = fmaf(s1, t3, x1.w + b1);
  *reinterpret_cast<float4*>(out + xoff) = o0;
  *reinterpret_cast<float4*>(out + xoff + HW) = o1;
}

// ---------- launch
extern "C" void kernel_launch(void* const* d_in, const int* in_sizes, int n_in,
                              void* d_out, int out_size, void* d_ws, size_t ws_size,
                              hipStream_t stream) {
  const float* x    = (const float*)d_in[0];
  const float* Wt   = (const float*)d_in[1];
  const float* Wp   = (const float*)d_in[2];
  const float* Wg   = (const float*)d_in[3];
  const float* Wz   = (const float*)d_in[4];
  const float* Wadj = (const float*)d_in[5];
  const float* bnag = (const float*)d_in[6];
  const float* bnab = (const float*)d_in[7];
  const float* bnam = (const float*)d_in[8];
  const float* bnav = (const float*)d_in[9];
  const float* Wwg  = (const float*)d_in[10];
  const float* bwgg = (const float*)d_in[11];
  const float* bwgb = (const float*)d_in[12];
  const float* bwgm = (const float*)d_in[13];
  const float* bwgv = (const float*)d_in[14];
  const float* gng  = (const float*)d_in[15];
  const float* gnb  = (const float*)d_in[16];

  char* ws = (char*)d_ws;
  // ws layout: xT 67108864 | Wh 786432 | t_ws 33554432 | att 4096 | tsum 4096 | tsq 4096 | sA 8192 | sB 8192
  _Float16* xT   = (_Float16*)(ws);
  _Float16* Wh   = (_Float16*)(ws + 67108864);
  _Float16* t_ws = (_Float16*)(ws + 67895296);
  float* att  = (float*)(ws + 101449728);
  float* tsum = (float*)(ws + 101453824);
  float* tsq  = (float*)(ws + 101457920);
  float* sA   = (float*)(ws + 101462016);
  float* sB   = (float*)(ws + 101470208);
  float* out  = (float*)d_out;
  if (ws_size < (size_t)101478400) return;

  // low-precision residue scratch lives in d_out (overwritten by k_out at the end)
  _Float16* xlo = (_Float16*)((char*)d_out);
  _Float16* Wlo = (_Float16*)((char*)d_out + 67108864);

  hipMemsetAsync(att, 0, 3 * 4096, stream);
  k_wcvt<<<dim3(1536), dim3(256), 0, stream>>>(Wt, Wp, Wg, Wh, Wlo);
  k_xpose<<<dim3(256, 8, 4), dim3(256), 0, stream>>>(x, xT, xlo);
  k_t<<<dim3(256, 4), dim3(512), 0, stream>>>(xT, Wh, t_ws, tsum, tsq);
  k_att<<<dim3(512, 4), dim3(512), 0, stream>>>(xT, xlo, Wh, Wlo, att);
  k_graph<<<dim3(1), dim3(1024), 0, stream>>>(att, tsum, tsq, Wadj, bnag, bnab, bnam, bnav,
                                              Wwg, bwgg, bwgb, bwgm, bwgv, Wz, gng, gnb, sA, sB);
  k_out<<<dim3(16384), dim3(256), 0, stream>>>(t_ws, x, sA, sB, out);
}

// Round 3
// 484.212 us; speedup vs baseline: 1.1208x; 1.1208x over previous
//
#include <hip/hip_runtime.h>

#define HW 16384
#define CIN 512
#define PL 256
#define EPSF 1e-5f
#define SLO 0.0009765625f   // 2^-10

using half8  = __attribute__((ext_vector_type(8))) _Float16;
using half4v = __attribute__((ext_vector_type(4))) _Float16;
using f32x4  = __attribute__((ext_vector_type(4))) float;

__device__ inline half8 cvt_hi8(float4 a, float4 b) {
  half8 h;
  h[0] = (_Float16)a.x; h[1] = (_Float16)a.y; h[2] = (_Float16)a.z; h[3] = (_Float16)a.w;
  h[4] = (_Float16)b.x; h[5] = (_Float16)b.y; h[6] = (_Float16)b.z; h[7] = (_Float16)b.w;
  return h;
}
__device__ inline half8 cvt_lo8(float4 a, float4 b, half8 hi) {
  half8 l;
  l[0] = (_Float16)((a.x - (float)hi[0]) * 1024.f);
  l[1] = (_Float16)((a.y - (float)hi[1]) * 1024.f);
  l[2] = (_Float16)((a.z - (float)hi[2]) * 1024.f);
  l[3] = (_Float16)((a.w - (float)hi[3]) * 1024.f);
  l[4] = (_Float16)((b.x - (float)hi[4]) * 1024.f);
  l[5] = (_Float16)((b.y - (float)hi[5]) * 1024.f);
  l[6] = (_Float16)((b.z - (float)hi[6]) * 1024.f);
  l[7] = (_Float16)((b.w - (float)hi[7]) * 1024.f);
  return l;
}

// ---------- kernel 0a: Wt f32 -> f16 (only t-weights need fp16; p,g stay f32 in k_V/k_red)
__global__ __launch_bounds__(256) void k_wcvt(const float* __restrict__ Wt,
                                              _Float16* __restrict__ Wh) {
  int idx = blockIdx.x * 256 + threadIdx.x;   // < 256*512
  Wh[idx] = (_Float16)Wt[idx];
}

// ---------- kernel 0b: x [b][c][hw] f32 -> xT [b][hw][c] f16 hi; also xsum[b][c] (atomic)
__global__ __launch_bounds__(256) void k_xpose(const float* __restrict__ x,
                                               _Float16* __restrict__ xT,
                                               float* __restrict__ xsum) {
  __shared__ float lds[64 * 65];
  int b = blockIdx.z;
  int cb = blockIdx.y << 6;
  int nb = blockIdx.x << 6;
  int tid = threadIdx.x;
  int q = tid & 15;
  int p = tid >> 4;
  const float* xb = x + ((size_t)b * CIN + cb) * HW + nb;
#pragma unroll
  for (int i = 0; i < 4; ++i) {
    int c = p + i * 16;
    float4 v = *reinterpret_cast<const float4*>(xb + (size_t)c * HW + (q << 2));
    lds[c * 65 + (q << 2) + 0] = v.x;
    lds[c * 65 + (q << 2) + 1] = v.y;
    lds[c * 65 + (q << 2) + 2] = v.z;
    lds[c * 65 + (q << 2) + 3] = v.w;
    float s = v.x + v.y + v.z + v.w;
    s += __shfl_xor(s, 1); s += __shfl_xor(s, 2);
    s += __shfl_xor(s, 4); s += __shfl_xor(s, 8);
    if (q == 0) atomicAdd(xsum + b * CIN + cb + c, s);
  }
  __syncthreads();
  size_t obase = ((size_t)b * HW + nb) * CIN + cb;
#pragma unroll
  for (int i = 0; i < 4; ++i) {
    int n = p + i * 16;
    half4v h;
#pragma unroll
    for (int j = 0; j < 4; ++j) h[j] = (_Float16)lds[(q * 4 + j) * 65 + n];
    *reinterpret_cast<half4v*>(xT + obase + (size_t)n * CIN + (q << 2)) = h;
  }
}

// ---------- kernel 1: t GEMM (hi only) -> t_ws fp16 [b][o][hw]
__global__ __launch_bounds__(512) void k_t(const _Float16* __restrict__ xT,
                                           const _Float16* __restrict__ Wh,
                                           _Float16* __restrict__ t_ws) {
  int tid = threadIdx.x;
  int wave = tid >> 6, lane = tid & 63;
  int l15 = lane & 15, l4 = lane >> 4;
  int b = blockIdx.y;
  int nb = blockIdx.x << 6;
  const _Float16* xTb = xT + (size_t)b * HW * CIN;

  const half8* ap[4];
#pragma unroll
  for (int nf = 0; nf < 4; ++nf)
    ap[nf] = reinterpret_cast<const half8*>(xTb + (size_t)(nb + nf * 16 + l15) * CIN + l4 * 8);
  const half8* bp[2];
#pragma unroll
  for (int ob = 0; ob < 2; ++ob) {
    int row = wave * 32 + ob * 16 + l15;
    bp[ob] = reinterpret_cast<const half8*>(Wh + (size_t)row * CIN + l4 * 8);
  }

  f32x4 acc[2][4];
#pragma unroll
  for (int ob = 0; ob < 2; ++ob)
#pragma unroll
    for (int nf = 0; nf < 4; ++nf) acc[ob][nf] = f32x4{0.f, 0.f, 0.f, 0.f};

#pragma unroll
  for (int ks = 0; ks < 16; ++ks) {
    half8 af[4], bf[2];
#pragma unroll
    for (int nf = 0; nf < 4; ++nf) af[nf] = ap[nf][ks * 4];
#pragma unroll
    for (int ob = 0; ob < 2; ++ob) bf[ob] = bp[ob][ks * 4];
#pragma unroll
    for (int ob = 0; ob < 2; ++ob)
#pragma unroll
      for (int nf = 0; nf < 4; ++nf)
        acc[ob][nf] = __builtin_amdgcn_mfma_f32_16x16x32_f16(af[nf], bf[ob], acc[ob][nf], 0, 0, 0);
  }

  __shared__ _Float16 tl[256 * 72];
#pragma unroll
  for (int ob = 0; ob < 2; ++ob)
#pragma unroll
    for (int nf = 0; nf < 4; ++nf)
#pragma unroll
      for (int r = 0; r < 4; ++r) {
        int o_l = wave * 32 + ob * 16 + l15;
        int n_l = nf * 16 + l4 * 4 + r;
        tl[o_l * 72 + n_l] = (_Float16)acc[ob][nf][r];
      }
  __syncthreads();
  _Float16* tb = t_ws + (((size_t)b * PL) << 14) + nb;
  for (int idx = tid; idx < 256 * 16; idx += 512) {
    int row = idx >> 4, seg = idx & 15;
    *reinterpret_cast<uint2*>(tb + (size_t)row * HW + (seg << 2)) =
        *reinterpret_cast<const uint2*>(&tl[row * 72 + (seg << 2)]);
  }
}

// ---------- kernel 2: Gram GEMM. GH[b][i][j] += Xh_i·Xh_j ; GC[b][i][j] += Xl_i·Xh_j
// grid (tile=ti*4+tj : 16, ks : 4, b : 4), 512 thr (8 waves). Tile 128x128, BK=64, K-chunk 4096.
__global__ __launch_bounds__(512) void k_gram(const float* __restrict__ x,
                                              float* __restrict__ GH,
                                              float* __restrict__ GC) {
  __shared__ _Float16 Ah[128 * 64], Al[128 * 64], Bh[128 * 64];
  int tile = blockIdx.x;
  int ti = tile >> 2, tj = tile & 3;
  int ks = blockIdx.y, b = blockIdx.z;
  int i0 = ti << 7, j0 = tj << 7;
  const float* xb = x + ((size_t)b * CIN) * HW;
  int tid = threadIdx.x;
  int wave = tid >> 6, lane = tid & 63, l15 = lane & 15, l4 = lane >> 4;
  int wr = wave >> 2, wc = wave & 3;
  int srow = tid >> 2, sseg = tid & 3;
  int ksbase = ks << 12;

  const float* pA0 = xb + (size_t)(i0 + srow) * HW + ksbase + sseg * 16;
  const float* pB0 = xb + (size_t)(j0 + srow) * HW + ksbase + sseg * 16;

  f32x4 hiAcc[4][2], c1Acc[4][2];
#pragma unroll
  for (int rf = 0; rf < 4; ++rf)
#pragma unroll
    for (int cf = 0; cf < 2; ++cf) {
      hiAcc[rf][cf] = f32x4{0.f, 0.f, 0.f, 0.f};
      c1Acc[rf][cf] = f32x4{0.f, 0.f, 0.f, 0.f};
    }

  // swizzled LDS write addrs (bytes): row*128 + (kb ^ ((row&7)<<4))
  int swz = (srow & 7) << 4;
  int wa0 = srow * 128 + ((sseg * 32) ^ swz);
  int wa1 = srow * 128 + ((sseg * 32 + 16) ^ swz);

  float4 va[4], vb[4];
#pragma unroll
  for (int u = 0; u < 4; ++u) {
    va[u] = *reinterpret_cast<const float4*>(pA0 + u * 4);
    vb[u] = *reinterpret_cast<const float4*>(pB0 + u * 4);
  }

  for (int step = 0; step < 64; ++step) {
    half8 ah0 = cvt_hi8(va[0], va[1]);
    half8 ah1 = cvt_hi8(va[2], va[3]);
    half8 al0 = cvt_lo8(va[0], va[1], ah0);
    half8 al1 = cvt_lo8(va[2], va[3], ah1);
    half8 bh0 = cvt_hi8(vb[0], vb[1]);
    half8 bh1 = cvt_hi8(vb[2], vb[3]);
    __syncthreads();
    *reinterpret_cast<half8*>((char*)Ah + wa0) = ah0;
    *reinterpret_cast<half8*>((char*)Ah + wa1) = ah1;
    *reinterpret_cast<half8*>((char*)Al + wa0) = al0;
    *reinterpret_cast<half8*>((char*)Al + wa1) = al1;
    *reinterpret_cast<half8*>((char*)Bh + wa0) = bh0;
    *reinterpret_cast<half8*>((char*)Bh + wa1) = bh1;
    __syncthreads();
    if (step < 63) {
      const float* nA = pA0 + (step + 1) * 64;
      const float* nB = pB0 + (step + 1) * 64;
#pragma unroll
      for (int u = 0; u < 4; ++u) {
        va[u] = *reinterpret_cast<const float4*>(nA + u * 4);
        vb[u] = *reinterpret_cast<const float4*>(nB + u * 4);
      }
    }
#pragma unroll
    for (int ksub = 0; ksub < 2; ++ksub) {
      half8 ah[4], al[4], bh[2];
      int kb = ksub * 64 + l4 * 16;
#pragma unroll
      for (int rf = 0; rf < 4; ++rf) {
        int rl = wr * 64 + rf * 16 + l15;
        int addr = rl * 128 + (kb ^ ((rl & 7) << 4));
        ah[rf] = *reinterpret_cast<const half8*>((char*)Ah + addr);
        al[rf] = *reinterpret_cast<const half8*>((char*)Al + addr);
      }
#pragma unroll
      for (int cf = 0; cf < 2; ++cf) {
        int cl = wc * 32 + cf * 16 + l15;
        int addr = cl * 128 + (kb ^ ((cl & 7) << 4));
        bh[cf] = *reinterpret_cast<const half8*>((char*)Bh + addr);
      }
#pragma unroll
      for (int rf = 0; rf < 4; ++rf)
#pragma unroll
        for (int cf = 0; cf < 2; ++cf) {
          hiAcc[rf][cf] = __builtin_amdgcn_mfma_f32_16x16x32_f16(ah[rf], bh[cf], hiAcc[rf][cf], 0, 0, 0);
          c1Acc[rf][cf] = __builtin_amdgcn_mfma_f32_16x16x32_f16(al[rf], bh[cf], c1Acc[rf][cf], 0, 0, 0);
        }
    }
  }

  float* GHb = GH + ((size_t)b << 18);
  float* GCb = GC + ((size_t)b << 18);
#pragma unroll
  for (int rf = 0; rf < 4; ++rf)
#pragma unroll
    for (int cf = 0; cf < 2; ++cf)
#pragma unroll
      for (int r = 0; r < 4; ++r) {
        int i = i0 + wr * 64 + rf * 16 + l4 * 4 + r;
        int j = j0 + wc * 32 + cf * 16 + l15;
        atomicAdd(GHb + ((size_t)i << 9) + j, hiAcc[rf][cf][r]);
        atomicAdd(GCb + ((size_t)i << 9) + j, c1Acc[rf][cf][r]);
      }
}

// ---------- kernel 3: Gs[i][j] = GH[i][j] + SLO*(GC[i][j] + GC[j][i])
__global__ __launch_bounds__(256) void k_sym(const float* __restrict__ GH,
                                             const float* __restrict__ GC,
                                             float* __restrict__ Gs) {
  __shared__ float T[64 * 65];
  int ti = blockIdx.x, tj = blockIdx.y, b = blockIdx.z;
  int i0 = ti << 6, j0 = tj << 6;
  int tid = threadIdx.x;
  int r = tid >> 2, cs = (tid & 3) << 4;
  const float* GCb = GC + ((size_t)b << 18);
  // stage T[r][c] = GC[j0+r][i0+c]
#pragma unroll
  for (int u = 0; u < 16; u += 4) {
    float4 v = *reinterpret_cast<const float4*>(GCb + ((size_t)(j0 + r) << 9) + i0 + cs + u);
    T[r * 65 + cs + u + 0] = v.x; T[r * 65 + cs + u + 1] = v.y;
    T[r * 65 + cs + u + 2] = v.z; T[r * 65 + cs + u + 3] = v.w;
  }
  __syncthreads();
  const float* GHb = GH + ((size_t)b << 18);
  float* Gsb = Gs + ((size_t)b << 18);
#pragma unroll
  for (int u = 0; u < 16; u += 4) {
    size_t off = ((size_t)(i0 + r) << 9) + j0 + cs + u;
    float4 h = *reinterpret_cast<const float4*>(GHb + off);
    float4 c = *reinterpret_cast<const float4*>(GCb + off);
    float4 o;
    o.x = h.x + SLO * (c.x + T[(cs + u + 0) * 65 + r]);
    o.y = h.y + SLO * (c.y + T[(cs + u + 1) * 65 + r]);
    o.z = h.z + SLO * (c.z + T[(cs + u + 2) * 65 + r]);
    o.w = h.w + SLO * (c.w + T[(cs + u + 3) * 65 + r]);
    *reinterpret_cast<float4*>(Gsb + off) = o;
  }
}

// ---------- kernel 4: V[b][ocol][i] = sum_j W[ocol][j] * Gs[b][i][j]   (ocol<256: Wg, else Wt)
__global__ __launch_bounds__(256) void k_V(const float* __restrict__ Gs,
                                           const float* __restrict__ Wg,
                                           const float* __restrict__ Wt,
                                           float* __restrict__ V) {
  __shared__ float Gl[64 * 65];
  __shared__ float Wl[64 * 65];
  int it = blockIdx.x, ot = blockIdx.y, b = blockIdx.z;
  int i0 = it << 6, o0 = ot << 6;
  int tid = threadIdx.x;
  int srow = tid >> 2, sseg = (tid & 3) << 4;
  const float* gsb = Gs + ((size_t)b << 18);
  int orow = o0 + srow;
  const float* wrow = (orow < 256) ? (Wg + (size_t)orow * 512) : (Wt + (size_t)(orow - 256) * 512);
  float acc[4][4];
#pragma unroll
  for (int a = 0; a < 4; ++a)
#pragma unroll
    for (int c = 0; c < 4; ++c) acc[a][c] = 0.f;
  int oy = (tid >> 4) << 2, ix = (tid & 15) << 2;
  for (int jc = 0; jc < 512; jc += 64) {
    __syncthreads();
#pragma unroll
    for (int u = 0; u < 16; u += 4) {
      float4 g = *reinterpret_cast<const float4*>(gsb + ((size_t)(i0 + srow) << 9) + jc + sseg + u);
      float4 w = *reinterpret_cast<const float4*>(wrow + jc + sseg + u);
      Gl[srow * 65 + sseg + u + 0] = g.x; Gl[srow * 65 + sseg + u + 1] = g.y;
      Gl[srow * 65 + sseg + u + 2] = g.z; Gl[srow * 65 + sseg + u + 3] = g.w;
      Wl[srow * 65 + sseg + u + 0] = w.x; Wl[srow * 65 + sseg + u + 1] = w.y;
      Wl[srow * 65 + sseg + u + 2] = w.z; Wl[srow * 65 + sseg + u + 3] = w.w;
    }
    __syncthreads();
    for (int j = 0; j < 64; ++j) {
      float w0 = Wl[(oy + 0) * 65 + j], w1 = Wl[(oy + 1) * 65 + j];
      float w2 = Wl[(oy + 2) * 65 + j], w3 = Wl[(oy + 3) * 65 + j];
      float g0 = Gl[(ix + 0) * 65 + j], g1 = Gl[(ix + 1) * 65 + j];
      float g2 = Gl[(ix + 2) * 65 + j], g3 = Gl[(ix + 3) * 65 + j];
      acc[0][0] += w0 * g0; acc[0][1] += w0 * g1; acc[0][2] += w0 * g2; acc[0][3] += w0 * g3;
      acc[1][0] += w1 * g0; acc[1][1] += w1 * g1; acc[1][2] += w1 * g2; acc[1][3] += w1 * g3;
      acc[2][0] += w2 * g0; acc[2][1] += w2 * g1; acc[2][2] += w2 * g2; acc[2][3] += w2 * g3;
      acc[3][0] += w3 * g0; acc[3][1] += w3 * g1; acc[3][2] += w3 * g2; acc[3][3] += w3 * g3;
    }
  }
  float* vb = V + ((size_t)b << 18);
#pragma unroll
  for (int a = 0; a < 4; ++a) {
    float4 vv = {acc[a][0], acc[a][1], acc[a][2], acc[a][3]};
    *reinterpret_cast<float4*>(vb + ((size_t)(o0 + oy + a) << 9) + i0 + ix) = vv;
  }
}

// ---------- kernel 5: att/tsq/tsum per (b,o)
__global__ __launch_bounds__(256) void k_red2(const float* __restrict__ V,
                                              const float* __restrict__ xsum,
                                              const float* __restrict__ Wp,
                                              const float* __restrict__ Wt,
                                              float* __restrict__ att,
                                              float* __restrict__ tsum,
                                              float* __restrict__ tsq) {
  int b = blockIdx.x, o = threadIdx.x;
  const float* vg = V + ((size_t)b << 18) + ((size_t)o << 9);
  const float* vt = V + ((size_t)b << 18) + ((size_t)(256 + o) << 9);
  const float* wp = Wp + (size_t)o * 512;
  const float* wt = Wt + (size_t)o * 512;
  const float* xs = xsum + b * CIN;
  float sa = 0.f, sq = 0.f, sm = 0.f;
  for (int i = 0; i < 512; i += 4) {
    float4 a = *reinterpret_cast<const float4*>(vg + i);
    float4 p = *reinterpret_cast<const float4*>(wp + i);
    float4 c = *reinterpret_cast<const float4*>(vt + i);
    float4 t = *reinterpret_cast<const float4*>(wt + i);
    float4 s = *reinterpret_cast<const float4*>(xs + i);
    sa += a.x * p.x + a.y * p.y + a.z * p.z + a.w * p.w;
    sq += c.x * t.x + c.y * t.y + c.z * t.z + c.w * t.w;
    sm += t.x * s.x + t.y * s.y + t.z * s.z + t.w * s.w;
  }
  att[b * PL + o] = sa;
  tsq[b * PL + o] = sq;
  tsum[b * PL + o] = sm;
}

// ---------- kernel 6: graph math (one block, 1024 threads)
__global__ __launch_bounds__(1024) void k_graph(
    const float* __restrict__ att, const float* __restrict__ tsum, const float* __restrict__ tsq,
    const float* __restrict__ W_adj, const float* __restrict__ bnag, const float* __restrict__ bnab,
    const float* __restrict__ bnam, const float* __restrict__ bnav,
    const float* __restrict__ W_wg, const float* __restrict__ bwgg, const float* __restrict__ bwgb,
    const float* __restrict__ bwgm, const float* __restrict__ bwgv,
    const float* __restrict__ Wz, const float* __restrict__ gng, const float* __restrict__ gnb,
    float* __restrict__ sA, float* __restrict__ sB) {
  __shared__ float att_l[4 * 256];
  __shared__ float z_l[4 * 256];
  __shared__ float zv_l[4 * 256];
  int tid = threadIdx.x;
  att_l[tid] = att[tid];
  __syncthreads();
  int b = tid >> 8, r = tid & 255, i = r >> 3, k = r & 7;
  float z1 = 0.f;
#pragma unroll
  for (int m = 0; m < 32; ++m) z1 += W_adj[i * 32 + m] * att_l[b * 256 + k * 32 + m];
  float inv = rsqrtf(bnav[i] + EPSF);
  float z = (z1 - bnam[i]) * inv * bnag[i] + bnab[i];
  z = fmaxf(z, 0.f) + att_l[b * 256 + k * 32 + i];
  z_l[b * 256 + i * 8 + k] = z;
  __syncthreads();
  float z2 = 0.f;
#pragma unroll
  for (int e = 0; e < 8; ++e) z2 += W_wg[k * 8 + e] * z_l[b * 256 + i * 8 + e];
  float inv2 = rsqrtf(bwgv[k] + EPSF);
  z2 = (z2 - bwgm[k]) * inv2 * bwgg[k] + bwgb[k];
  zv_l[b * 256 + i * 8 + k] = fmaxf(z2, 0.f);
  __syncthreads();
  int g = r;
  float s = zv_l[b * 256 + g];
  float m1 = tsum[b * 256 + g] * (1.f / 16384.f);
  float m2 = tsq[b * 256 + g] * (1.f / 16384.f);
  float a0 = Wz[2 * g] * s, a1 = Wz[2 * g + 1] * s;
  float mu = 0.5f * (a0 + a1) * m1;
  float ey2 = 0.5f * (a0 * a0 + a1 * a1) * m2;
  float var = ey2 - mu * mu;
  float invg = rsqrtf(var + EPSF);
  int c = b * CIN + 2 * g;
  sA[c]     = a0 * invg * gng[2 * g];
  sA[c + 1] = a1 * invg * gng[2 * g + 1];
  sB[c]     = gnb[2 * g]     - mu * invg * gng[2 * g];
  sB[c + 1] = gnb[2 * g + 1] - mu * invg * gng[2 * g + 1];
}

// ---------- kernel 7: out = sA*t + sB + x
__global__ __launch_bounds__(256) void k_out(const _Float16* __restrict__ t_ws,
                                             const float* __restrict__ x,
                                             const float* __restrict__ sA,
                                             const float* __restrict__ sB,
                                             float* __restrict__ out) {
  int blk = blockIdx.x;                 // 16384 = 4b * 256g * 16
  int b = blk >> 12;
  int g = (blk >> 4) & 255;
  int hw0 = (((blk & 15) << 8) + threadIdx.x) << 2;
  half4v tv = *reinterpret_cast<const half4v*>(t_ws + (((size_t)(b * PL + g)) << 14) + hw0);
  size_t xoff = (((size_t)(b * CIN + 2 * g)) << 14) + hw0;
  float4 x0 = *reinterpret_cast<const float4*>(x + xoff);
  float4 x1 = *reinterpret_cast<const float4*>(x + xoff + HW);
  int c = b * CIN + 2 * g;
  float s0 = sA[c], s1 = sA[c + 1], b0 = sB[c], b1 = sB[c + 1];
  float t0 = (float)tv[0], t1 = (float)tv[1], t2 = (float)tv[2], t3 = (float)tv[3];
  float4 o0, o1;
  o0.x = fmaf(s0, t0, x0.x + b0); o0.y = fmaf(s0, t1, x0.y + b0);
  o0.z = fmaf(s0, t2, x0.z + b0); o0.w = fmaf(s0, t3, x0.w + b0);
  o1.x = fmaf(s1, t0, x1.x + b1); o1.y = fmaf(s1, t1, x1.y + b1);
  o1.z = fmaf(s1, t2, x1.z + b1); o1.w = fmaf(s1, t3, x1.w + b1);
  *reinterpret_cast<float4*>(out + xoff) = o0;
  *reinterpret_cast<float4*>(out + xoff + HW) = o1;
}

// ---------- launch
extern "C" void kernel_launch(void* const* d_in, const int* in_sizes, int n_in,
                              void* d_out, int out_size, void* d_ws, size_t ws_size,
                              hipStream_t stream) {
  const float* x    = (const float*)d_in[0];
  const float* Wt   = (const float*)d_in[1];
  const float* Wp   = (const float*)d_in[2];
  const float* Wg   = (const float*)d_in[3];
  const float* Wz   = (const float*)d_in[4];
  const float* Wadj = (const float*)d_in[5];
  const float* bnag = (const float*)d_in[6];
  const float* bnab = (const float*)d_in[7];
  const float* bnam = (const float*)d_in[8];
  const float* bnav = (const float*)d_in[9];
  const float* Wwg  = (const float*)d_in[10];
  const float* bwgg = (const float*)d_in[11];
  const float* bwgb = (const float*)d_in[12];
  const float* bwgm = (const float*)d_in[13];
  const float* bwgv = (const float*)d_in[14];
  const float* gng  = (const float*)d_in[15];
  const float* gnb  = (const float*)d_in[16];

  char* ws = (char*)d_ws;
  _Float16* xT   = (_Float16*)(ws);                    // 67108864
  _Float16* Wh   = (_Float16*)(ws + 67108864);         // 262144
  _Float16* t_ws = (_Float16*)(ws + 67371008);         // 33554432
  float* xsum = (float*)(ws + 100925440);              // 8192
  float* att  = (float*)(ws + 100933632);              // 4096
  float* tsum = (float*)(ws + 100937728);              // 4096
  float* tsq  = (float*)(ws + 100941824);              // 4096
  float* sA   = (float*)(ws + 100945920);              // 8192
  float* sB   = (float*)(ws + 100954112);              // 8192
  if (ws_size < (size_t)100962304) return;

  // Gram buffers live in d_out (overwritten by k_out at the end)
  float* GH = (float*)((char*)d_out);                  // 4194304
  float* GC = (float*)((char*)d_out + 4194304);        // 4194304
  float* Gs = (float*)((char*)d_out + 8388608);        // 4194304
  float* V  = (float*)((char*)d_out + 12582912);       // 4194304
  float* out = (float*)d_out;

  hipMemsetAsync(d_out, 0, 8388608, stream);           // GH, GC
  hipMemsetAsync(xsum, 0, 8192, stream);
  k_wcvt<<<dim3(512), dim3(256), 0, stream>>>(Wt, Wh);
  k_xpose<<<dim3(256, 8, 4), dim3(256), 0, stream>>>(x, xT, xsum);
  k_t<<<dim3(256, 4), dim3(512), 0, stream>>>(xT, Wh, t_ws);
  k_gram<<<dim3(16, 4, 4), dim3(512), 0, stream>>>(x, GH, GC);
  k_sym<<<dim3(8, 8, 4), dim3(256), 0, stream>>>(GH, GC, Gs);
  k_V<<<dim3(8, 8, 4), dim3(256), 0, stream>>>(Gs, Wg, Wt, V);
  k_red2<<<dim3(4), dim3(256), 0, stream>>>(V, xsum, Wp, Wt, att, tsum, tsq);
  k_graph<<<dim3(1), dim3(1024), 0, stream>>>(att, tsum, tsq, Wadj, bnag, bnab, bnam, bnav,
                                              Wwg, bwgg, bwgb, bwgm, bwgv, Wz, gng, gnb, sA, sB);
  k_out<<<dim3(16384), dim3(256), 0, stream>>>(t_ws, x, sA, sB, out);
}